// Round 1
// baseline (409.617 us; speedup 1.0000x reference)
//
#include <hip/hip_runtime.h>
#include <hip/hip_bf16.h>
#include <stdint.h>

typedef _Float16 f16;
typedef _Float16 f16x4 __attribute__((ext_vector_type(4)));
typedef _Float16 f16x8 __attribute__((ext_vector_type(8)));
typedef float f32x4 __attribute__((ext_vector_type(4)));

// async global->LDS copy, 16B per lane. LDS dest must be wave-uniform-base + lane*16.
#define ASYNC_COPY16(gsrc, ldst)                                                   \
    __builtin_amdgcn_global_load_lds(                                              \
        (__attribute__((address_space(1))) void*)(gsrc),                           \
        (__attribute__((address_space(3))) void*)(ldst), 16, 0, 0)

// ---------------------------------------------------------------------------
// fp32 -> f16 conversion, 4 elems/thread (float4 load, 8B store)
// ---------------------------------------------------------------------------
__global__ __launch_bounds__(256) void cvt_f32_to_f16(const float* __restrict__ in,
                                                      f16* __restrict__ out, int n4) {
    int i = blockIdx.x * 256 + threadIdx.x;
    if (i >= n4) return;
    float4 v = ((const float4*)in)[i];
    f16x4 o;
    o.x = (f16)v.x; o.y = (f16)v.y; o.z = (f16)v.z; o.w = (f16)v.w;
    ((f16x4*)out)[i] = o;
}

// ---------------------------------------------------------------------------
// C = A(MxK) * B(NxK)^T + bias, f16 inputs, fp32 accumulate.
// 128x128 tile, BK=32, 256 threads = 4 waves in 2x2, each wave 64x64 via
// 4x4 grid of 16x16x32 MFMAs. global_load_lds(16B) staging, m97 structure.
// STORE_F16: 1 -> store f16 (for h), 0 -> store fp32 (for out).
// ---------------------------------------------------------------------------
template <int STORE_F16>
__global__ __launch_bounds__(256) void gemm_bt(const f16* __restrict__ A,
                                               const f16* __restrict__ Bm,
                                               const float* __restrict__ bias,
                                               void* __restrict__ Cout,
                                               int M, int N, int K) {
    constexpr int BM = 128, BN = 128, BK = 32;
    __shared__ __align__(16) f16 sA[BM * BK];
    __shared__ __align__(16) f16 sB[BN * BK];

    const int tid   = threadIdx.x;
    const int lane  = tid & 63;
    const int wave  = tid >> 6;   // 0..3
    const int waveM = wave >> 1;  // 0..1
    const int waveN = wave & 1;   // 0..1

    const int bm = blockIdx.y * BM;
    const int bn = blockIdx.x * BN;

    // staging map: lane -> (row = lane/4, 16B seg = lane%4); wave w covers rows
    // [w*16, w*16+16) then +64. LDS layout row-major [128][32], no padding
    // (global_load_lds requires lds_off == wave_base + lane*16).
    const int srow = lane >> 2;
    const int scol = (lane & 3) * 8;  // in halves (8 halves = 16B)

    const f16* Aptr = A + (size_t)bm * K;
    const f16* Bptr = Bm + (size_t)bn * K;

    f32x4 acc[4][4] = {};

    const int quad = lane >> 4;
    const int l16  = lane & 15;

    for (int k0 = 0; k0 < K; k0 += BK) {
        {
            const int r0 = wave * 16 + srow;
            const int r1 = r0 + 64;
            ASYNC_COPY16(Aptr + (size_t)r0 * K + k0 + scol, &sA[r0 * BK + scol]);
            ASYNC_COPY16(Aptr + (size_t)r1 * K + k0 + scol, &sA[r1 * BK + scol]);
            ASYNC_COPY16(Bptr + (size_t)r0 * K + k0 + scol, &sB[r0 * BK + scol]);
            ASYNC_COPY16(Bptr + (size_t)r1 * K + k0 + scol, &sB[r1 * BK + scol]);
        }
        __syncthreads();  // drains vmcnt (global_load_lds) + barrier

        f16x8 af[4], bf[4];
#pragma unroll
        for (int mi = 0; mi < 4; mi++)
            af[mi] = *(const f16x8*)&sA[(waveM * 64 + mi * 16 + l16) * BK + quad * 8];
#pragma unroll
        for (int ni = 0; ni < 4; ni++)
            bf[ni] = *(const f16x8*)&sB[(waveN * 64 + ni * 16 + l16) * BK + quad * 8];

#pragma unroll
        for (int mi = 0; mi < 4; mi++)
#pragma unroll
            for (int ni = 0; ni < 4; ni++)
                acc[mi][ni] = __builtin_amdgcn_mfma_f32_16x16x32_f16(af[mi], bf[ni],
                                                                     acc[mi][ni], 0, 0, 0);
        __syncthreads();  // protect LDS before next stage
    }

    // epilogue: C/D layout col = lane&15, row = quad*4 + reg
#pragma unroll
    for (int ni = 0; ni < 4; ni++) {
        const int col = bn + waveN * 64 + ni * 16 + l16;
        const float bv = bias[col];
#pragma unroll
        for (int mi = 0; mi < 4; mi++) {
            const int row0 = bm + waveM * 64 + mi * 16 + quad * 4;
#pragma unroll
            for (int r = 0; r < 4; r++) {
                float v = acc[mi][ni][r] + bv;
                if (STORE_F16)
                    ((f16*)Cout)[(size_t)(row0 + r) * N + col] = (f16)v;
                else
                    ((float*)Cout)[(size_t)(row0 + r) * N + col] = v;
            }
        }
    }
}

// ---------------------------------------------------------------------------
// replicator: per row r, dot = sum_k y*out; out = y*(out - dot). In-place on out.
// one block (256 thr) per row, float4 loads.
// ---------------------------------------------------------------------------
__global__ __launch_bounds__(256) void replicator(const float* __restrict__ y,
                                                  float* __restrict__ out, int N) {
    const int row = blockIdx.x;
    const float4* y4 = (const float4*)(y + (size_t)row * N);
    float4* o4 = (float4*)(out + (size_t)row * N);
    const int n4 = N / 4;

    float p = 0.f;
    for (int i = threadIdx.x; i < n4; i += 256) {
        float4 a = y4[i], b = o4[i];
        p += a.x * b.x + a.y * b.y + a.z * b.z + a.w * b.w;
    }
#pragma unroll
    for (int off = 32; off > 0; off >>= 1) p += __shfl_down(p, off, 64);

    __shared__ float sred[4];
    if ((threadIdx.x & 63) == 0) sred[threadIdx.x >> 6] = p;
    __syncthreads();
    const float dot = sred[0] + sred[1] + sred[2] + sred[3];

    for (int i = threadIdx.x; i < n4; i += 256) {
        float4 a = y4[i], b = o4[i];
        float4 r;
        r.x = a.x * (b.x - dot);
        r.y = a.y * (b.y - dot);
        r.z = a.z * (b.z - dot);
        r.w = a.w * (b.w - dot);
        o4[i] = r;
    }
}

extern "C" void kernel_launch(void* const* d_in, const int* in_sizes, int n_in,
                              void* d_out, int out_size, void* d_ws, size_t ws_size,
                              hipStream_t stream) {
    // inputs: 0=t(1), 1=y(B*N), 2=W1(N*N), 3=b1(N), 4=W2(N*N), 5=b2(N)
    const float* y  = (const float*)d_in[1];
    const float* W1 = (const float*)d_in[2];
    const float* b1 = (const float*)d_in[3];
    const float* W2 = (const float*)d_in[4];
    const float* b2 = (const float*)d_in[5];

    const int N = in_sizes[3];            // 4096
    const int B = in_sizes[1] / N;        // 2048
    float* out = (float*)d_out;

    // workspace: yb (B*N f16) | wb (N*N f16, reused for W1 then W2) | hb (B*N f16)
    f16* yb = (f16*)d_ws;
    f16* wb = yb + (size_t)B * N;
    f16* hb = wb + (size_t)N * N;

    const int yn4 = (B * N) / 4;
    const int wn4 = (N * N) / 4;

    // 1) y -> f16, W1 -> f16
    cvt_f32_to_f16<<<yn4 / 256, 256, 0, stream>>>(y, yb, yn4);
    cvt_f32_to_f16<<<wn4 / 256, 256, 0, stream>>>(W1, wb, wn4);

    // 2) h = f16(y @ W1^T + b1)
    dim3 g1(N / 128, B / 128);
    gemm_bt<1><<<g1, 256, 0, stream>>>(yb, wb, b1, hb, B, N, N);

    // 3) W2 -> f16 (reuse wb; stream-ordered after GEMM1)
    cvt_f32_to_f16<<<wn4 / 256, 256, 0, stream>>>(W2, wb, wn4);

    // 4) out = fp32(h @ W2^T + b2)
    gemm_bt<0><<<g1, 256, 0, stream>>>(hb, wb, b2, out, B, N, N);

    // 5) out = y * (out - rowdot(y, out))
    replicator<<<B, 256, 0, stream>>>(y, out, N);
}